// Round 1
// 245.811 us; speedup vs baseline: 1.0043x; 1.0043x over previous
//
#include <hip/hip_runtime.h>
#include <math.h>

#define B_   2
#define S_   1024
#define HID_ 2048
#define HQ_  32
#define HKV_ 8
#define HD_  64
#define NQKV 3072   // HID + 2*HKV*HD

using short8  = __attribute__((ext_vector_type(8))) short;
using floatx4 = __attribute__((ext_vector_type(4))) float;

__device__ __forceinline__ unsigned short f2bf(float x) {
    unsigned int u = __builtin_bit_cast(unsigned int, x);
    u += 0x7FFFu + ((u >> 16) & 1u);
    return (unsigned short)(u >> 16);
}
__device__ __forceinline__ float bf2f(unsigned short u) {
    return __builtin_bit_cast(float, (unsigned int)u << 16);
}

__device__ __forceinline__ void gl_lds16(const unsigned short* g, unsigned short* l) {
    __builtin_amdgcn_global_load_lds(
        (const __attribute__((address_space(1))) void*)g,
        (__attribute__((address_space(3))) void*)l, 16, 0, 0);
}

// ---------------------------------------------------------------------------
// QKV GEMM, SPLIT-K=2 (768 blocks = 3/CU). m97 skeleton: 128x128 tile, BK=32,
// 4 waves in 2x2 of 64x64. bid decode:
//   bid<512:  Q  (N in [0,2048)):  n=(bid&15)*128, m=((bid>>4)&15)*128, z=bid>>8
//   bid>=512: KV (N in [2048,3072)): b'=bid-512, n=2048+(b'&7)*128,
//             m=((b'>>3)&15)*128, z=b'>>7
// K chunk = [z*1024, z*1024+1024). Output: bf16 partials
//   Q:  Qp  + z*2048*2048  (row stride 2048)
//   KV: KVp + z*2048*1024  (row stride 1024, col = n-2048)
// ---------------------------------------------------------------------------
__global__ __launch_bounds__(256) void gemm_qkv(const unsigned short* __restrict__ A,
                                                const unsigned short* __restrict__ Bt,
                                                unsigned short* __restrict__ Qp,
                                                unsigned short* __restrict__ KVp) {
    __shared__ __align__(16) unsigned short As[128 * 32];
    __shared__ __align__(16) unsigned short Bs[128 * 32];

    int bid = blockIdx.x;
    int m0, n0, z, Nw, nc0;
    unsigned short* C;
    if (bid < 512) {
        n0 = (bid & 15) * 128; m0 = ((bid >> 4) & 15) * 128; z = bid >> 8;
        C = Qp + (size_t)z * 2048 * 2048; Nw = 2048; nc0 = n0;
    } else {
        bid -= 512;
        n0 = 2048 + (bid & 7) * 128; m0 = ((bid >> 3) & 15) * 128; z = bid >> 7;
        C = KVp + (size_t)z * 2048 * 1024; Nw = 1024; nc0 = n0 - 2048;
    }
    const int kbase = z * 1024;

    const int tid  = threadIdx.x;
    const int w    = tid >> 6;
    const int lane = tid & 63;
    const int col  = lane & 15;
    const int quad = lane >> 4;
    const int wm = (w >> 1) * 64;
    const int wn = (w & 1) * 64;

    const int srow = lane >> 2;
    const int skof = (lane & 3) * 8;
    const unsigned short* Ag = A  + (size_t)(m0 + srow) * HID_ + skof;
    const unsigned short* Bg = Bt + (size_t)(n0 + srow) * HID_ + skof;
    const int rb = w * 16;

    floatx4 acc[4][4] = {};

    for (int k0 = kbase; k0 < kbase + 1024; k0 += 32) {
        gl_lds16(Ag + (size_t)(rb     ) * HID_ + k0, &As[(rb     ) * 32]);
        gl_lds16(Ag + (size_t)(rb + 64) * HID_ + k0, &As[(rb + 64) * 32]);
        gl_lds16(Bg + (size_t)(rb     ) * HID_ + k0, &Bs[(rb     ) * 32]);
        gl_lds16(Bg + (size_t)(rb + 64) * HID_ + k0, &Bs[(rb + 64) * 32]);
        __syncthreads();

        short8 af[4], bfr[4];
#pragma unroll
        for (int i = 0; i < 4; ++i)
            af[i] = *(const short8*)&As[(wm + i * 16 + col) * 32 + quad * 8];
#pragma unroll
        for (int j = 0; j < 4; ++j)
            bfr[j] = *(const short8*)&Bs[(wn + j * 16 + col) * 32 + quad * 8];
#pragma unroll
        for (int i = 0; i < 4; ++i)
#pragma unroll
            for (int j = 0; j < 4; ++j)
                acc[i][j] = __builtin_amdgcn_mfma_f32_16x16x32_bf16(
                    af[i], bfr[j], acc[i][j], 0, 0, 0);
        __syncthreads();
    }

#pragma unroll
    for (int i = 0; i < 4; ++i)
#pragma unroll
        for (int j = 0; j < 4; ++j)
#pragma unroll
            for (int r = 0; r < 4; ++r)
                C[(size_t)(m0 + wm + i * 16 + quad * 4 + r) * Nw
                  + (nc0 + wn + j * 16 + col)] = f2bf(acc[i][j][r]);
}

// ---------------------------------------------------------------------------
// Wo GEMM, SPLIT-K=2 (512 blocks). z=0 -> fp32 direct to out; z=1 -> bf16 p1.
// ---------------------------------------------------------------------------
__global__ __launch_bounds__(256) void gemm_wo(const unsigned short* __restrict__ A,
                                               const unsigned short* __restrict__ Bt,
                                               float* __restrict__ Cf,
                                               unsigned short* __restrict__ Cp1) {
    __shared__ __align__(16) unsigned short As[128 * 32];
    __shared__ __align__(16) unsigned short Bs[128 * 32];

    const int m0 = blockIdx.y * 128;
    const int n0 = blockIdx.x * 128;
    const int z  = blockIdx.z;
    const int kbase = z * 1024;

    const int tid  = threadIdx.x;
    const int w    = tid >> 6;
    const int lane = tid & 63;
    const int col  = lane & 15;
    const int quad = lane >> 4;
    const int wm = (w >> 1) * 64;
    const int wn = (w & 1) * 64;

    const int srow = lane >> 2;
    const int skof = (lane & 3) * 8;
    const unsigned short* Ag = A  + (size_t)(m0 + srow) * HID_ + skof;
    const unsigned short* Bg = Bt + (size_t)(n0 + srow) * HID_ + skof;
    const int rb = w * 16;

    floatx4 acc[4][4] = {};

    for (int k0 = kbase; k0 < kbase + 1024; k0 += 32) {
        gl_lds16(Ag + (size_t)(rb     ) * HID_ + k0, &As[(rb     ) * 32]);
        gl_lds16(Ag + (size_t)(rb + 64) * HID_ + k0, &As[(rb + 64) * 32]);
        gl_lds16(Bg + (size_t)(rb     ) * HID_ + k0, &Bs[(rb     ) * 32]);
        gl_lds16(Bg + (size_t)(rb + 64) * HID_ + k0, &Bs[(rb + 64) * 32]);
        __syncthreads();

        short8 af[4], bfr[4];
#pragma unroll
        for (int i = 0; i < 4; ++i)
            af[i] = *(const short8*)&As[(wm + i * 16 + col) * 32 + quad * 8];
#pragma unroll
        for (int j = 0; j < 4; ++j)
            bfr[j] = *(const short8*)&Bs[(wn + j * 16 + col) * 32 + quad * 8];
#pragma unroll
        for (int i = 0; i < 4; ++i)
#pragma unroll
            for (int j = 0; j < 4; ++j)
                acc[i][j] = __builtin_amdgcn_mfma_f32_16x16x32_bf16(
                    af[i], bfr[j], acc[i][j], 0, 0, 0);
        __syncthreads();
    }

#pragma unroll
    for (int i = 0; i < 4; ++i)
#pragma unroll
        for (int j = 0; j < 4; ++j)
#pragma unroll
            for (int r = 0; r < 4; ++r) {
                size_t off = (size_t)(m0 + wm + i * 16 + quad * 4 + r) * HID_
                           + (n0 + wn + j * 16 + col);
                if (z == 0) Cf[off] = acc[i][j][r];
                else        Cp1[off] = f2bf(acc[i][j][r]);
            }
}

// out[i] += bf2f(p1[i]), vectorized (4 per thread). 4096 blocks x 256.
__global__ __launch_bounds__(256) void reduce_wo(float* __restrict__ out,
                                                 const unsigned short* __restrict__ p1) {
    int i4 = (blockIdx.x * 256 + threadIdx.x) * 4;
    float4 o = *(float4*)&out[i4];
    ushort4 p = *(const ushort4*)&p1[i4];
    o.x += bf2f(p.x); o.y += bf2f(p.y); o.z += bf2f(p.z); o.w += bf2f(p.w);
    *(float4*)&out[i4] = o;
}

// ---------------------------------------------------------------------------
// fp32 -> bf16 elementwise (X)
// ---------------------------------------------------------------------------
__global__ __launch_bounds__(256) void convert_x(const float* __restrict__ in,
                                                 unsigned short* __restrict__ out) {
    int tid = blockIdx.x * 256 + threadIdx.x;
    float4 v = *(const float4*)&in[(size_t)tid * 4];
    ushort4 o = {f2bf(v.x), f2bf(v.y), f2bf(v.z), f2bf(v.w)};
    *(ushort4*)&out[(size_t)tid * 4] = o;
}

// ---------------------------------------------------------------------------
// Weight transposes (fp32 KxN -> bf16 NxK), 32x32 LDS tiles.
// ---------------------------------------------------------------------------
__global__ __launch_bounds__(256) void transpose_qkv(const float* __restrict__ Wq,
                                                     const float* __restrict__ Wk,
                                                     const float* __restrict__ Wv,
                                                     unsigned short* __restrict__ WcatT) {
    __shared__ float tile[32][33];
    int bid = blockIdx.x;
    const float* W;
    unsigned short* WT;
    int N, tn0, tk0;
    if (bid < 4096) {
        W = Wq; WT = WcatT; N = HID_;
        tn0 = (bid & 63) * 32; tk0 = (bid >> 6) * 32;
    } else if (bid < 5120) {
        bid -= 4096;
        W = Wk; WT = WcatT + (size_t)HID_ * HID_; N = 512;
        tn0 = (bid & 15) * 32; tk0 = (bid >> 4) * 32;
    } else {
        bid -= 5120;
        W = Wv; WT = WcatT + (size_t)(HID_ + 512) * HID_; N = 512;
        tn0 = (bid & 15) * 32; tk0 = (bid >> 4) * 32;
    }
    const int r  = threadIdx.x >> 3;
    const int c4 = (threadIdx.x & 7) * 4;
    float4 v = *(const float4*)&W[(size_t)(tk0 + r) * N + tn0 + c4];
    tile[r][c4 + 0] = v.x;
    tile[r][c4 + 1] = v.y;
    tile[r][c4 + 2] = v.z;
    tile[r][c4 + 3] = v.w;
    __syncthreads();
    ushort4 o = {f2bf(tile[c4 + 0][r]), f2bf(tile[c4 + 1][r]),
                 f2bf(tile[c4 + 2][r]), f2bf(tile[c4 + 3][r])};
    *(ushort4*)&WT[(size_t)(tn0 + r) * HID_ + tk0 + c4] = o;
}

__global__ __launch_bounds__(256) void transpose_wo(const float* __restrict__ Wo,
                                                    unsigned short* __restrict__ WoT) {
    __shared__ float tile[32][33];
    int bid = blockIdx.x;
    const int tn0 = (bid & 63) * 32;
    const int tk0 = (bid >> 6) * 32;
    const int r  = threadIdx.x >> 3;
    const int c4 = (threadIdx.x & 7) * 4;
    float4 v = *(const float4*)&Wo[(size_t)(tk0 + r) * HID_ + tn0 + c4];
    tile[r][c4 + 0] = v.x;
    tile[r][c4 + 1] = v.y;
    tile[r][c4 + 2] = v.z;
    tile[r][c4 + 3] = v.w;
    __syncthreads();
    ushort4 o = {f2bf(tile[c4 + 0][r]), f2bf(tile[c4 + 1][r]),
                 f2bf(tile[c4 + 2][r]), f2bf(tile[c4 + 3][r])};
    *(ushort4*)&WoT[(size_t)(tn0 + r) * HID_ + tk0 + c4] = o;
}

// ---------------------------------------------------------------------------
// Fused split-K reduce + RoPE + layout conversion.
// ---------------------------------------------------------------------------
__global__ __launch_bounds__(256) void convert_qkv(const unsigned short* __restrict__ Qp,
                                                   const unsigned short* __restrict__ KVp,
                                                   const float* __restrict__ cosT,
                                                   const float* __restrict__ sinT,
                                                   unsigned short* __restrict__ Qbf,
                                                   unsigned short* __restrict__ Kbf,
                                                   unsigned short* __restrict__ Vt) {
    const size_t QSTR  = (size_t)2048 * 2048;   // Q partial stride (elems)
    const size_t KVSTR = (size_t)2048 * 1024;   // KV partial stride
    int tid = blockIdx.x * 256 + threadIdx.x;
    const int NQ = B_ * S_ * HQ_ * 32;
    const int NK = B_ * S_ * HKV_ * 32;
    if (tid < NQ) {
        int d = tid & 31;
        int h = (tid >> 5) & (HQ_ - 1);
        int s = (tid >> 10) & (S_ - 1);
        int b = tid >> 20;
        const unsigned short* row = Qp + (size_t)(b * S_ + s) * 2048 + h * HD_;
        float x0 = bf2f(row[d])      + bf2f(row[QSTR + d]);
        float x1 = bf2f(row[d + 32]) + bf2f(row[QSTR + d + 32]);
        float c0 = cosT[s * HD_ + d],      s0 = sinT[s * HD_ + d];
        float c1 = cosT[s * HD_ + d + 32], s1 = sinT[s * HD_ + d + 32];
        unsigned short* orow = Qbf + ((size_t)(b * HQ_ + h) * S_ + s) * HD_;
        orow[d]      = f2bf((x0 * c0 - x1 * s0) * 0.125f);
        orow[d + 32] = f2bf((x1 * c1 + x0 * s1) * 0.125f);
    } else if (tid < NQ + NK) {
        tid -= NQ;
        int d  = tid & 31;
        int kv = (tid >> 5) & (HKV_ - 1);
        int s  = (tid >> 8) & (S_ - 1);
        int b  = tid >> 18;
        const unsigned short* row = KVp + (size_t)(b * S_ + s) * 1024 + kv * HD_;
        float x0 = bf2f(row[d])      + bf2f(row[KVSTR + d]);
        float x1 = bf2f(row[d + 32]) + bf2f(row[KVSTR + d + 32]);
        float c0 = cosT[s * HD_ + d],      s0 = sinT[s * HD_ + d];
        float c1 = cosT[s * HD_ + d + 32], s1 = sinT[s * HD_ + d + 32];
        unsigned short* orow = Kbf + ((size_t)(b * HKV_ + kv) * S_ + s) * HD_;
        orow[d]      = f2bf(x0 * c0 - x1 * s0);
        orow[d + 32] = f2bf(x1 * c1 + x0 * s1);
    } else {
        tid -= NQ + NK;
        int s4 = tid & 255;
        int d  = (tid >> 8) & (HD_ - 1);
        int kv = (tid >> 14) & (HKV_ - 1);
        int b  = tid >> 17;
        int s  = s4 * 4;
        const unsigned short* base =
            KVp + ((size_t)(b * S_ + s)) * 1024 + 512 + kv * HD_ + d;
        ushort4 o;
#pragma unroll
        for (int j = 0; j < 4; ++j) {
            float v = bf2f(base[(size_t)j * 1024]) +
                      bf2f(base[KVSTR + (size_t)j * 1024]);
            ((unsigned short*)&o)[j] = f2bf(v);
        }
        *(ushort4*)&Vt[((size_t)(b * HKV_ + kv) * HD_ + d) * S_ + s] = o;
    }
}

// ---------------------------------------------------------------------------
// Flash attention v2: 32 queries/wave (2 q-tiles), double-buffered K/V in
// LDS with XOR-swizzled 16B slots (conflict-free ds_read_b128), staged via
// pre-swizzled global source addresses (global_load_lds dest stays linear).
// Block = 4 waves = 4 q-heads sharing one kv head. Grid (32, 8, 2).
// ---------------------------------------------------------------------------
__global__ __launch_bounds__(256) void attn_mfma(const unsigned short* __restrict__ Qbf,
                                                 const unsigned short* __restrict__ Kbf,
                                                 const unsigned short* __restrict__ Vt,
                                                 unsigned short* __restrict__ Ctx) {
    const int tq = 31 - blockIdx.x;     // longest blocks first
    const int kv = blockIdx.y;
    const int b  = blockIdx.z;
    const int w    = threadIdx.x >> 6;
    const int lane = threadIdx.x & 63;
    const int col  = lane & 15;
    const int quad = lane >> 4;

    const int h   = kv * 4 + w;
    const int bh  = b * HQ_ + h;
    const int bkv = b * HKV_ + kv;
    const int qw  = 32 * tq;

    // [dbuf][row*64 + d], 128B rows; 16B slot s at row r holds logical slot s^(r&7)
    __shared__ __align__(16) unsigned short sK[2][64 * 64];
    __shared__ __align__(16) unsigned short sV[2][64 * 64];
    __shared__ __align__(16) unsigned short sP[4][32 * 72];
    unsigned short* myP = sP[w];

    // Q fragments: 2 q-tiles x 2 halves of HD
    short8 bq[2][2];
#pragma unroll
    for (int u = 0; u < 2; ++u) {
        const unsigned short* qrow = Qbf + ((size_t)bh * S_ + qw + 16 * u + col) * HD_;
        bq[u][0] = *(const short8*)&qrow[quad * 8];
        bq[u][1] = *(const short8*)&qrow[32 + quad * 8];
    }

    const unsigned short* Kbase = Kbf + (size_t)bkv * S_ * HD_;
    const unsigned short* Vbase = Vt  + (size_t)bkv * HD_ * S_;

    // staging: per gl_lds16 call a wave fills 8 rows x 8 slots (1 KiB).
    // row = r0 + 8c + (lane>>3); dest slot = lane&7; source slot pre-swizzled.
    const int sr  = lane >> 3;
    const int ssl = (lane & 7) ^ sr;     // (dest slot) ^ (row&7)
    const int r0  = 16 * w;

    floatx4 acc[2][4] = {};
    float m_i[2] = {-1e30f, -1e30f};
    float l_i[2] = {0.f, 0.f};

    const int nsteps = (qw + 95) >> 6;   // ceil((qw+32)/64)

    // prologue: stage step 0 into buf 0
#pragma unroll
    for (int c = 0; c < 2; ++c) {
        const int row = r0 + 8 * c + sr;
        gl_lds16(Kbase + (size_t)row * HD_ + ssl * 8, &sK[0][(r0 + 8 * c) * 64]);
        gl_lds16(Vbase + (size_t)row * S_ + ssl * 8,  &sV[0][(r0 + 8 * c) * 64]);
    }
    __syncthreads();

    int cur = 0;
    for (int it = 0; it < nsteps; ++it) {
        const int k0 = it * 64;

        // issue next-step staging early; the trailing __syncthreads drains it
        if (it + 1 < nsteps) {
            const int kn = k0 + 64;
#pragma unroll
            for (int c = 0; c < 2; ++c) {
                const int row = r0 + 8 * c + sr;
                gl_lds16(Kbase + (size_t)(kn + row) * HD_ + ssl * 8,
                         &sK[cur ^ 1][(r0 + 8 * c) * 64]);
                gl_lds16(Vbase + (size_t)row * S_ + kn + ssl * 8,
                         &sV[cur ^ 1][(r0 + 8 * c) * 64]);
            }
        }

        // QK^T: K fragments shared across both q-tiles
        floatx4 sc[2][4];
        __builtin_amdgcn_s_setprio(1);
#pragma unroll
        for (int tt = 0; tt < 4; ++tt) {
            const int krow = 16 * tt + col;
            const unsigned short* kr = &sK[cur][krow * 64];
            short8 ak0 = *(const short8*)&kr[((quad    ) ^ (krow & 7)) * 8];
            short8 ak1 = *(const short8*)&kr[((quad + 4) ^ (krow & 7)) * 8];
#pragma unroll
            for (int u = 0; u < 2; ++u) {
                floatx4 z = {0.f, 0.f, 0.f, 0.f};
                z = __builtin_amdgcn_mfma_f32_16x16x32_bf16(ak0, bq[u][0], z, 0, 0, 0);
                z = __builtin_amdgcn_mfma_f32_16x16x32_bf16(ak1, bq[u][1], z, 0, 0, 0);
                sc[u][tt] = z;
            }
        }
        __builtin_amdgcn_s_setprio(0);

        // online softmax per q-tile
#pragma unroll
        for (int u = 0; u < 2; ++u) {
            const int qbase = qw + 16 * u;
            const int myq   = qbase + col;
            if (k0 + 63 > qbase) {
#pragma unroll
                for (int tt = 0; tt < 4; ++tt)
#pragma unroll
                    for (int r = 0; r < 4; ++r)
                        if (k0 + 16 * tt + quad * 4 + r > myq) sc[u][tt][r] = -1e30f;
            }
            float vmax = sc[u][0][0];
#pragma unroll
            for (int tt = 0; tt < 4; ++tt)
#pragma unroll
                for (int r = 0; r < 4; ++r)
                    vmax = fmaxf(vmax, sc[u][tt][r]);
            vmax = fmaxf(vmax, __shfl_xor(vmax, 16, 64));
            vmax = fmaxf(vmax, __shfl_xor(vmax, 32, 64));
            const float mnew  = fmaxf(m_i[u], vmax);
            const float alpha = __expf(m_i[u] - mnew);
            m_i[u] = mnew;
            float lsum = 0.f;
#pragma unroll
            for (int tt = 0; tt < 4; ++tt) {
                float p0 = __expf(sc[u][tt][0] - mnew);
                float p1 = __expf(sc[u][tt][1] - mnew);
                float p2 = __expf(sc[u][tt][2] - mnew);
                float p3 = __expf(sc[u][tt][3] - mnew);
                lsum += (p0 + p1) + (p2 + p3);
                ushort4 pk = {f2bf(p0), f2bf(p1), f2bf(p2), f2bf(p3)};
                *(ushort4*)&myP[(16 * u + col) * 72 + 16 * tt + quad * 4] = pk;
            }
            lsum += __shfl_xor(lsum, 16, 64);
            lsum += __shfl_xor(lsum, 32, 64);
            l_i[u] = l_i[u] * alpha + lsum;
            float a_r[4];
#pragma unroll
            for (int r = 0; r < 4; ++r)
                a_r[r] = __shfl(alpha, quad * 4 + r, 64);
#pragma unroll
            for (int nt = 0; nt < 4; ++nt)
#pragma unroll
                for (int r = 0; r < 4; ++r)
                    acc[u][nt][r] *= a_r[r];
        }

        // PV: V fragments shared across both q-tiles
        short8 pa[2][2];
#pragma unroll
        for (int u = 0; u < 2; ++u) {
            pa[u][0] = *(const short8*)&myP[(16 * u + col) * 72 + quad * 8];
            pa[u][1] = *(const short8*)&myP[(16 * u + col) * 72 + 32 + quad * 8];
        }
        __builtin_amdgcn_s_setprio(1);
#pragma unroll
        for (int nt = 0; nt < 4; ++nt) {
            const int vrow = 16 * nt + col;
            const unsigned short* vr = &sV[cur][vrow * 64];
            short8 vb0 = *(const short8*)&vr[((quad    ) ^ (vrow & 7)) * 8];
            short8 vb1 = *(const short8*)&vr[((quad + 4) ^ (vrow & 7)) * 8];
#pragma unroll
            for (int u = 0; u < 2; ++u) {
                acc[u][nt] = __builtin_amdgcn_mfma_f32_16x16x32_bf16(pa[u][0], vb0, acc[u][nt], 0, 0, 0);
                acc[u][nt] = __builtin_amdgcn_mfma_f32_16x16x32_bf16(pa[u][1], vb1, acc[u][nt], 0, 0, 0);
            }
        }
        __builtin_amdgcn_s_setprio(0);

        __syncthreads();
        cur ^= 1;
    }

#pragma unroll
    for (int u = 0; u < 2; ++u) {
        const float invl = 1.0f / l_i[u];
        float inv_r[4];
#pragma unroll
        for (int r = 0; r < 4; ++r)
            inv_r[r] = __shfl(invl, quad * 4 + r, 64);
#pragma unroll
        for (int nt = 0; nt < 4; ++nt)
#pragma unroll
            for (int r = 0; r < 4; ++r)
                Ctx[(size_t)(b * S_ + qw + 16 * u + quad * 4 + r) * HID_
                    + h * HD_ + nt * 16 + col] = f2bf(acc[u][nt][r] * inv_r[r]);
    }
}

// ---------------------------------------------------------------------------
extern "C" void kernel_launch(void* const* d_in, const int* in_sizes, int n_in,
                              void* d_out, int out_size, void* d_ws, size_t ws_size,
                              hipStream_t stream) {
    const float* X    = (const float*)d_in[0];
    const float* cosT = (const float*)d_in[1];
    const float* sinT = (const float*)d_in[2];
    const float* Wq   = (const float*)d_in[3];
    const float* Wk   = (const float*)d_in[4];
    const float* Wv   = (const float*)d_in[5];
    const float* Wo   = (const float*)d_in[6];

    const int M = B_ * S_;          // 2048
    const size_t MB = 1024u * 1024u;

    // Memory schedule (ws 28 MiB, d_out 16 MiB), lifetime-aliased:
    //  1 convert_x:     Xbf -> ws[0,8)
    //  2 transpose_qkv: WcatT -> ws[8,20)
    //  3 gemm_qkv:      Q partials (2x8 MiB bf16) -> d_out; KV partials
    //                   (2x4 MiB bf16) -> ws[20,28)
    //  4 convert_qkv:   reduce+RoPE -> Qbf ws[0,8), Kbf ws[8,10), Vt ws[10,12)
    //  5 transpose_wo:  WoT -> ws[12,20)
    //  6 attn:          Ctxbf -> ws[20,28)
    //  7 gemm_wo:       z=0 fp32 -> d_out; z=1 bf16 p1 -> ws[0,8)
    //  8 reduce_wo:     d_out += p1 (in place)
    char* ws = (char*)d_ws;
    unsigned short* Xbf   = (unsigned short*)(ws);
    unsigned short* Qbf   = (unsigned short*)(ws);
    unsigned short* WcatT = (unsigned short*)(ws + 8 * MB);
    unsigned short* Kbf   = (unsigned short*)(ws + 8 * MB);
    unsigned short* Vt    = (unsigned short*)(ws + 10 * MB);
    unsigned short* WoT   = (unsigned short*)(ws + 12 * MB);
    unsigned short* KVp   = (unsigned short*)(ws + 20 * MB);
    unsigned short* Ctxbf = (unsigned short*)(ws + 20 * MB);
    unsigned short* Wop1  = (unsigned short*)(ws);
    unsigned short* Qp    = (unsigned short*)d_out;
    float* out = (float*)d_out;

    // 1. X -> bf16
    convert_x<<<(M * HID_ / 4) / 256, 256, 0, stream>>>(X, Xbf);

    // 2. Wq|Wk|Wv -> WcatT
    transpose_qkv<<<6144, 256, 0, stream>>>(Wq, Wk, Wv, WcatT);

    // 3. QKV projection, split-K=2 (768 blocks)
    gemm_qkv<<<768, 256, 0, stream>>>(Xbf, WcatT, Qp, KVp);

    // 4. Fused split-K reduce + RoPE + layout conversion
    {
        int total = B_ * S_ * HQ_ * 32 + B_ * S_ * HKV_ * 32
                  + B_ * HKV_ * HD_ * (S_ / 4);
        convert_qkv<<<total / 256, 256, 0, stream>>>(Qp, KVp, cosT, sinT,
                                                     Qbf, Kbf, Vt);
    }

    // 5. Wo -> WoT
    transpose_wo<<<4096, 256, 0, stream>>>(Wo, WoT);

    // 6. Flash attention (32 q/wave, dbuf, swizzled LDS)
    attn_mfma<<<dim3(32, HKV_, B_), 256, 0, stream>>>(Qbf, Kbf, Vt, Ctxbf);

    // 7. Output projection, split-K=2 (512 blocks)
    gemm_wo<<<dim3(16, 16, 2), 256, 0, stream>>>(Ctxbf, WoT, out, Wop1);

    // 8. out += p1
    reduce_wo<<<(M * HID_ / 4) / 256, 256, 0, stream>>>(out, Wop1);
}